// Round 10
// baseline (1715.765 us; speedup 1.0000x reference)
//
#include <hip/hip_runtime.h>

typedef unsigned short u16;
typedef __attribute__((ext_vector_type(8))) unsigned short ushort8;
typedef __attribute__((ext_vector_type(4))) unsigned short ushort4v;
typedef __attribute__((ext_vector_type(8))) short bf16x8;
typedef __attribute__((ext_vector_type(4))) float f32x4;
typedef __attribute__((ext_vector_type(2))) unsigned int uint2v;
typedef __attribute__((ext_vector_type(4))) unsigned int uint4v;

#define LB    2048
#define DIM   1024
#define NCAT  5248
#define MROWS 8192

__device__ __forceinline__ float b2f(u16 u) {
    unsigned int x = ((unsigned int)u) << 16;
    return __builtin_bit_cast(float, x);
}
__device__ __forceinline__ u16 f2b(float f) {
    unsigned int u = __builtin_bit_cast(unsigned int, f);
    u = u + 0x7FFFu + ((u >> 16) & 1u);
    return (u16)(u >> 16);
}
__device__ __forceinline__ float sigm(float x) { return 1.0f / (1.0f + __expf(-x)); }

// async global->LDS, 16B per lane; LDS dest = wave-uniform base + lane*16.
__device__ __forceinline__ void gload_lds16(const u16* g, u16* l) {
    __builtin_amdgcn_global_load_lds((const __attribute__((address_space(1))) void*)g,
                                     (__attribute__((address_space(3))) void*)l, 16, 0, 0);
}

#define MFMA(a, b, c) __builtin_amdgcn_mfma_f32_16x16x32_bf16((a), (b), (c), 0, 0, 0)

// ---------------- elementwise prep ----------------
__global__ void f32_to_bf16(const float* __restrict__ src, u16* __restrict__ dst, int n) {
    int i = (blockIdx.x * 256 + threadIdx.x) * 4;
    if (i >= n) return;
    float4 v = *(const float4*)(src + i);
    ushort4v u;
    u[0] = f2b(v.x); u[1] = f2b(v.y); u[2] = f2b(v.z); u[3] = f2b(v.w);
    *(ushort4v*)(dst + i) = u;
}

// src [1024, cols] f32  ->  dst[c*1024 + r] bf16   (grid: (cols, 4), block 256)
__global__ void transpose_f32_bf16(const float* __restrict__ src, u16* __restrict__ dst, int cols) {
    const int cidx = blockIdx.x;
    const int r = blockIdx.y * 256 + threadIdx.x;
    dst[(size_t)cidx * 1024 + r] = f2b(src[(size_t)r * cols + cidx]);
}

__global__ void fill_zero_u16(u16* __restrict__ dst, int n) {
    int i = blockIdx.x * 256 + threadIdx.x;
    if (i < n) dst[i] = 0;
}

// ---------------- bf16 MFMA GEMM (m97 structure):  C[M,N] = A[M,K] * Bt[N,K]^T ----------------
template <int OUT_IS_F32>
__global__ __launch_bounds__(256) void gemm_bt(const u16* __restrict__ A,
                                               const u16* __restrict__ Bt,
                                               void* __restrict__ Cv,
                                               int M, int N, int K) {
    __shared__ u16 lds_a[128 * 32];
    __shared__ u16 lds_b[128 * 32];
    const int tid = threadIdx.x;
    const int m0 = blockIdx.y * 128;
    const int n0 = blockIdx.x * 128;
    const int w = tid >> 6;
    const int l = tid & 63;
    const int wm = w >> 1, wn = w & 1;
    const int lr = l & 15, kg = l >> 4;

    f32x4 acc[4][4];
#pragma unroll
    for (int m = 0; m < 4; ++m)
#pragma unroll
        for (int n = 0; n < 4; ++n)
            acc[m][n] = f32x4{0.f, 0.f, 0.f, 0.f};

    const int scol = (l & 3) * 8;

    for (int kt = 0; kt < K; kt += 32) {
#pragma unroll
        for (int ld = 0; ld < 2; ++ld) {
            const int row = w * 32 + ld * 16 + (l >> 2);
            gload_lds16(A + (size_t)(m0 + row) * K + kt + scol, &lds_a[(w * 32 + ld * 16) * 32]);
            gload_lds16(Bt + (size_t)(n0 + row) * K + kt + scol, &lds_b[(w * 32 + ld * 16) * 32]);
        }
        __syncthreads();
        bf16x8 af[4], bfv[4];
#pragma unroll
        for (int m = 0; m < 4; ++m)
            af[m] = *(const bf16x8*)&lds_a[(wm * 64 + m * 16 + lr) * 32 + kg * 8];
#pragma unroll
        for (int n = 0; n < 4; ++n)
            bfv[n] = *(const bf16x8*)&lds_b[(wn * 64 + n * 16 + lr) * 32 + kg * 8];
#pragma unroll
        for (int m = 0; m < 4; ++m)
#pragma unroll
            for (int n = 0; n < 4; ++n)
                acc[m][n] = MFMA(af[m], bfv[n], acc[m][n]);
        __syncthreads();
    }

#pragma unroll
    for (int m = 0; m < 4; ++m) {
#pragma unroll
        for (int n = 0; n < 4; ++n) {
            const int col = n0 + wn * 64 + n * 16 + lr;
#pragma unroll
            for (int j = 0; j < 4; ++j) {
                const int row = m0 + wm * 64 + m * 16 + kg * 4 + j;
                if (OUT_IS_F32)
                    ((float*)Cv)[(size_t)row * N + col] = acc[m][n][j];
                else
                    ((u16*)Cv)[(size_t)row * N + col] = f2b(acc[m][n][j]);
            }
        }
    }
}

// ---------------- causal depthwise conv (K=4) + bias + SiLU (+scale) ----------------
__global__ __launch_bounds__(256) void conv_silu(const u16* __restrict__ pre,
                                                 u16* __restrict__ dst,
                                                 const float* __restrict__ w,
                                                 const float* __restrict__ bias,
                                                 float scale, int col_off) {
    const int row = blockIdx.x;       // b*L + l
    const int l = row & (LB - 1);
    const int ch = threadIdx.x * 4;
    const float4* wv = (const float4*)(w + ch * 4);
    float wt[4][4];
#pragma unroll
    for (int c = 0; c < 4; ++c) {
        float4 t = wv[c];
        wt[c][0] = t.x; wt[c][1] = t.y; wt[c][2] = t.z; wt[c][3] = t.w;
    }
    float acc[4] = {bias[ch + 0], bias[ch + 1], bias[ch + 2], bias[ch + 3]};
#pragma unroll
    for (int dd = 0; dd < 4; ++dd) {
        if (l - 3 + dd >= 0) {
            ushort4v vv = *(const ushort4v*)(pre + (size_t)(row - 3 + dd) * NCAT + col_off + ch);
#pragma unroll
            for (int c = 0; c < 4; ++c) acc[c] += b2f(vv[c]) * wt[c][dd];
        }
    }
    ushort4v outv;
#pragma unroll
    for (int c = 0; c < 4; ++c) {
        float a = acc[c];
        outv[c] = f2b(a * sigm(a) * scale);
    }
    *(ushort4v*)(dst + (size_t)row * DIM + ch) = outv;
}

// ---------------- chunked delta-rule scan (T=16) ----------------
// 64 blocks = (b, h, half-of-DV); 1 wave (64 threads) per block.
// Per chunk: MFMA phase 1 computes c0 = S0 k_t, P = S0 q_t, Gram m = K K^T,
// N = Q K^T; a short serial loop (per-channel, no cross-lane) solves for
// u_t = -beta (S_{t-1} k_t - v_t) via ubar_j = u_j / G_j; MFMA phase 2
// produces outputs o_t = G_t*(P + sum_{j<=t} ubar_j (k_j.q_t)) and the state
// update S = G_15*(S0 + Ubar K).  S lives in 128 f32 frag registers.
__global__ __launch_bounds__(64, 1) void scan_chunked(const u16* __restrict__ qb,
                                                      const u16* __restrict__ kb,
                                                      const u16* __restrict__ vb,
                                                      const u16* __restrict__ pre,
                                                      const float* __restrict__ ba,
                                                      const float* __restrict__ bb,
                                                      float* __restrict__ o) {
    const int bid = blockIdx.x;        // 0..63
    const int bh = bid >> 1;           // 0..31
    const int half = bid & 1;
    const int h = bh & 7, b = bh >> 3;
    const int lane = threadIdx.x;      // 0..63
    const int lr = lane & 15, lg = lane >> 4;
    const size_t row0 = (size_t)b * LB;

    __shared__ u16 Kc[16 * 136];      // [t][k] row-major, padded
    __shared__ u16 Qc[16 * 136];
    __shared__ u16 KT[128 * 36];      // [k][j] transposed K, j padded (16..35 zero)
    __shared__ u16 S0b[64 * 136];     // [v][k] bf16 copy of S
    __shared__ u16 Ul[64 * 40];       // [v][j] ubar bf16, j 16..31 zero
    __shared__ u16 Ll[16 * 40];       // [t][j] masked QK gram bf16, j 16..31 zero
    __shared__ float c0T[64 * 20];    // [v][t]
    __shared__ float Gl[64 * 20];     // [v][t]
    __shared__ float ml[16 * 20];     // [t][t']

    for (int i = lane; i < 64 * 136; i += 64) S0b[i] = 0;
    for (int i = lane; i < 64 * 40; i += 64) Ul[i] = 0;
    for (int i = lane; i < 16 * 40; i += 64) Ll[i] = 0;
    for (int i = lane; i < 128 * 36; i += 64) KT[i] = 0;

    const int ch = h * 128 + half * 64 + lane;
    const float bav = ba[ch];
    const float bbv = bb[h];

    const u16* kbase = kb + row0 * DIM + h * 128;
    const u16* qbase = qb + row0 * DIM + h * 128;
    const u16* vbase = vb + row0 * DIM + (size_t)ch;
    const u16* abase = pre + row0 * NCAT + 3072 + (size_t)ch;
    const u16* bbase = pre + row0 * NCAT + 5120 + h;
    float* obase = o + row0 * DIM + h * 128 + half * 64;

    f32x4 S[8][4];
#pragma unroll
    for (int kt = 0; kt < 8; ++kt)
#pragma unroll
        for (int vt = 0; vt < 4; ++vt)
            S[kt][vt] = f32x4{0.f, 0.f, 0.f, 0.f};

    for (int c = 0; c < 128; ++c) {
        // ---- staging: K,Q rows ----
        {
            const int st = lane >> 2;
            const int sc = (lane & 3) * 32;
            const u16* kr = kbase + (size_t)(c * 16 + st) * DIM + sc;
            const u16* qr = qbase + (size_t)(c * 16 + st) * DIM + sc;
#pragma unroll
            for (int i = 0; i < 4; ++i) {
                *(ushort8*)&Kc[st * 136 + sc + i * 8] = *(const ushort8*)(kr + i * 8);
                *(ushort8*)&Qc[st * 136 + sc + i * 8] = *(const ushort8*)(qr + i * 8);
            }
        }
        // ---- staging: K transpose (lane owns k = 2*lane, 2*lane+1) ----
        {
            unsigned int kd[16];
#pragma unroll
            for (int t = 0; t < 16; ++t)
                kd[t] = *(const unsigned int*)(kbase + (size_t)(c * 16 + t) * DIM + lane * 2);
#pragma unroll
            for (int i = 0; i < 4; ++i) {
                uint2v lo, hi;
                lo[0] = __builtin_amdgcn_perm(kd[4 * i + 1], kd[4 * i + 0], 0x05040100u);
                lo[1] = __builtin_amdgcn_perm(kd[4 * i + 3], kd[4 * i + 2], 0x05040100u);
                hi[0] = __builtin_amdgcn_perm(kd[4 * i + 1], kd[4 * i + 0], 0x07060302u);
                hi[1] = __builtin_amdgcn_perm(kd[4 * i + 3], kd[4 * i + 2], 0x07060302u);
                *(uint2v*)&KT[(2 * lane) * 36 + i * 4] = lo;
                *(uint2v*)&KT[(2 * lane + 1) * 36 + i * 4] = hi;
            }
        }
        // ---- staging: v, a->G, beta (per-channel, in registers) ----
        float G[16], invG[16], bf_[16], bva[16];
        {
#pragma unroll
            for (int t = 0; t < 16; ++t) {
                float vat = b2f(vbase[(size_t)(c * 16 + t) * DIM]);
                float aft = sigm(b2f(abase[(size_t)(c * 16 + t) * NCAT]) + bav);
                bf_[t] = sigm(b2f(bbase[(size_t)(c * 16 + t) * NCAT]) + bbv);
                bva[t] = bf_[t] * vat;
                G[t] = (t == 0) ? aft : G[t - 1] * aft;
            }
#pragma unroll
            for (int t = 0; t < 16; ++t) invG[t] = __builtin_amdgcn_rcpf(G[t]);
#pragma unroll
            for (int q = 0; q < 4; ++q) {
                float4 gq = {G[4 * q], G[4 * q + 1], G[4 * q + 2], G[4 * q + 3]};
                *(float4*)&Gl[lane * 20 + 4 * q] = gq;
            }
        }

        // ---- MFMA phase 1 ----
        bf16x8 kfrag[4], qfrag[4];
#pragma unroll
        for (int ks = 0; ks < 4; ++ks) {
            kfrag[ks] = *(const bf16x8*)&Kc[lr * 136 + lg * 8 + ks * 32];
            qfrag[ks] = *(const bf16x8*)&Qc[lr * 136 + lg * 8 + ks * 32];
        }
        f32x4 D2[4];
#pragma unroll
        for (int vt = 0; vt < 4; ++vt) {
            bf16x8 sb[4];
#pragma unroll
            for (int ks = 0; ks < 4; ++ks)
                sb[ks] = *(const bf16x8*)&S0b[(vt * 16 + lr) * 136 + lg * 8 + ks * 32];
            f32x4 d1 = f32x4{0.f, 0.f, 0.f, 0.f};
            f32x4 d2 = f32x4{0.f, 0.f, 0.f, 0.f};
#pragma unroll
            for (int ks = 0; ks < 4; ++ks) {
                d1 = MFMA(kfrag[ks], sb[ks], d1);   // D1[t][v] = k_t . S0[v,:]
                d2 = MFMA(qfrag[ks], sb[ks], d2);   // D2[t][v] = q_t . S0[v,:]
            }
#pragma unroll
            for (int j = 0; j < 4; ++j)
                c0T[(vt * 16 + lr) * 20 + lg * 4 + j] = d1[j];
            D2[vt] = d2;
        }
        {
            f32x4 d3 = f32x4{0.f, 0.f, 0.f, 0.f};
            f32x4 d4 = f32x4{0.f, 0.f, 0.f, 0.f};
#pragma unroll
            for (int ks = 0; ks < 4; ++ks) {
                d3 = MFMA(kfrag[ks], kfrag[ks], d3);   // m[t][t'] = k_t . k_t'
                d4 = MFMA(qfrag[ks], kfrag[ks], d4);   // N[t][j] = q_t . k_j
            }
#pragma unroll
            for (int j = 0; j < 4; ++j) {
                const int trow = lg * 4 + j;
                ml[trow * 20 + lr] = d3[j];
                Ll[trow * 40 + lr] = (lr <= trow) ? f2b(d4[j]) : (u16)0;
            }
        }

        // ---- serial core (per-channel, no cross-lane) ----
        {
            float c0v[16], eacc[16];
#pragma unroll
            for (int q = 0; q < 4; ++q) {
                float4 cq = *(const float4*)&c0T[lane * 20 + 4 * q];
                c0v[4 * q] = cq.x; c0v[4 * q + 1] = cq.y;
                c0v[4 * q + 2] = cq.z; c0v[4 * q + 3] = cq.w;
            }
#pragma unroll
            for (int t = 0; t < 16; ++t) eacc[t] = 0.f;
#pragma unroll
            for (int t = 0; t < 16; ++t) {
                float e = (t == 0) ? c0v[0] : G[t - 1] * (c0v[t] + eacc[t]);
                float u = fmaf(-bf_[t], e, bva[t]);     // u = -beta*(e - v)
                float ub = u * invG[t];
                Ul[lane * 40 + t] = f2b(ub);
                if (t < 15) {
                    float mrow[16];
#pragma unroll
                    for (int q = 0; q < 4; ++q) {
                        float4 mq = *(const float4*)&ml[t * 20 + 4 * q];
                        mrow[4 * q] = mq.x; mrow[4 * q + 1] = mq.y;
                        mrow[4 * q + 2] = mq.z; mrow[4 * q + 3] = mq.w;
                    }
#pragma unroll
                    for (int tp = t + 1; tp < 16; ++tp)
                        eacc[tp] = fmaf(ub, mrow[tp], eacc[tp]);
                }
            }
        }

        // ---- MFMA phase 2 ----
        bf16x8 ufr[4];
#pragma unroll
        for (int vt = 0; vt < 4; ++vt)
            ufr[vt] = *(const bf16x8*)&Ul[(vt * 16 + lr) * 40 + lg * 8];
        // state update: S[k][v] += sum_j K[j][k] * ubar_j[v]
#pragma unroll
        for (int kt = 0; kt < 8; ++kt) {
            uint2v alo = *(const uint2v*)&KT[(kt * 16 + lr) * 36 + lg * 8];
            uint2v ahi = *(const uint2v*)&KT[(kt * 16 + lr) * 36 + lg * 8 + 4];
            uint4v av;
            av[0] = alo[0]; av[1] = alo[1]; av[2] = ahi[0]; av[3] = ahi[1];
            bf16x8 afr = __builtin_bit_cast(bf16x8, av);
#pragma unroll
            for (int vt = 0; vt < 4; ++vt)
                S[kt][vt] = MFMA(afr, ufr[vt], S[kt][vt]);
        }
        // outputs: o[t][v] = G_t[v] * (P[t][v] + sum_{j<=t} L[t][j] ubar_j[v])
        {
            bf16x8 lfr = *(const bf16x8*)&Ll[lr * 40 + lg * 8];
#pragma unroll
            for (int vt = 0; vt < 4; ++vt) {
                f32x4 d5 = MFMA(lfr, ufr[vt], D2[vt]);
                float4 gq = *(const float4*)&Gl[(vt * 16 + lr) * 20 + lg * 4];
                float gv[4] = {gq.x, gq.y, gq.z, gq.w};
#pragma unroll
                for (int j = 0; j < 4; ++j)
                    obase[(size_t)(c * 16 + lg * 4 + j) * DIM + vt * 16 + lr] = gv[j] * d5[j];
            }
        }
        // decay S by G_15 and refresh bf16 copy for next chunk
#pragma unroll
        for (int vt = 0; vt < 4; ++vt) {
            const float gT = Gl[(vt * 16 + lr) * 20 + 15];
#pragma unroll
            for (int kt = 0; kt < 8; ++kt) {
                S[kt][vt][0] *= gT; S[kt][vt][1] *= gT;
                S[kt][vt][2] *= gT; S[kt][vt][3] *= gT;
                ushort4v sv;
                sv[0] = f2b(S[kt][vt][0]); sv[1] = f2b(S[kt][vt][1]);
                sv[2] = f2b(S[kt][vt][2]); sv[3] = f2b(S[kt][vt][3]);
                *(ushort4v*)&S0b[(vt * 16 + lr) * 136 + kt * 16 + lg * 4] = sv;
            }
        }
    }
}

// ---------------- LayerNorm(DV) + sigmoid gate -> bf16 ----------------
__global__ __launch_bounds__(256) void ln_gate(const float* __restrict__ o,
                                               const u16* __restrict__ pre,
                                               const float* __restrict__ ln_g,
                                               const float* __restrict__ ln_b,
                                               u16* __restrict__ o2) {
    const int row = blockIdx.x;
    const int tid = threadIdx.x;
    const int h = tid >> 5;
    const int lg = tid & 31;
    const int d0 = lg * 4;
    float4 x = *(const float4*)(o + (size_t)row * DIM + h * 128 + d0);
    float s = x.x + x.y + x.z + x.w;
    float ss = x.x * x.x + x.y * x.y + x.z * x.z + x.w * x.w;
#pragma unroll
    for (int m = 1; m <= 16; m <<= 1) {
        s += __shfl_xor(s, m);
        ss += __shfl_xor(ss, m);
    }
    const float mu = s * (1.f / 128.f);
    const float var = ss * (1.f / 128.f) - mu * mu;
    const float inv = rsqrtf(var + 1e-5f);
    ushort4v gp = *(const ushort4v*)(pre + (size_t)row * NCAT + 4096 + h * 128 + d0);
    float4 lg4 = *(const float4*)(ln_g + d0);
    float4 lb4 = *(const float4*)(ln_b + d0);
    float xv[4] = {x.x, x.y, x.z, x.w};
    float gv[4] = {lg4.x, lg4.y, lg4.z, lg4.w};
    float bv[4] = {lb4.x, lb4.y, lb4.z, lb4.w};
    ushort4v outv;
#pragma unroll
    for (int q = 0; q < 4; ++q) {
        float y = (xv[q] - mu) * inv * gv[q] + bv[q];
        y *= sigm(b2f(gp[q]));
        outv[q] = f2b(y);
    }
    *(ushort4v*)(o2 + (size_t)row * DIM + h * 128 + d0) = outv;
}

extern "C" void kernel_launch(void* const* d_in, const int* in_sizes, int n_in,
                              void* d_out, int out_size, void* d_ws, size_t ws_size,
                              hipStream_t stream) {
    const float* x   = (const float*)d_in[0];
    const float* Wq  = (const float*)d_in[1];
    const float* Wk  = (const float*)d_in[2];
    const float* Wv  = (const float*)d_in[3];
    const float* Wa  = (const float*)d_in[4];
    const float* ba  = (const float*)d_in[5];
    const float* Wb  = (const float*)d_in[6];
    const float* bb  = (const float*)d_in[7];
    const float* Wg  = (const float*)d_in[8];
    const float* Wo  = (const float*)d_in[9];
    const float* cqw = (const float*)d_in[10];
    const float* cqb = (const float*)d_in[11];
    const float* ckw = (const float*)d_in[12];
    const float* ckb = (const float*)d_in[13];
    const float* cvw = (const float*)d_in[14];
    const float* cvb = (const float*)d_in[15];
    const float* lng = (const float*)d_in[16];
    const float* lnb = (const float*)d_in[17];

    const size_t NEED = (size_t)MROWS * DIM * 2
                      + (size_t)NCAT * DIM * 2
                      + (size_t)DIM * DIM * 2
                      + (size_t)MROWS * NCAT * 2
                      + 3 * (size_t)MROWS * DIM * 2
                      + (size_t)MROWS * DIM * 4
                      + (size_t)MROWS * DIM * 2;
    if (ws_size < NEED) return;

    char* p = (char*)d_ws;
    u16* x_bf  = (u16*)p; p += (size_t)MROWS * DIM * 2;
    u16* wcatT = (u16*)p; p += (size_t)NCAT * DIM * 2;
    u16* woT   = (u16*)p; p += (size_t)DIM * DIM * 2;
    u16* pre   = (u16*)p; p += (size_t)MROWS * NCAT * 2;
    u16* qbuf  = (u16*)p; p += (size_t)MROWS * DIM * 2;
    u16* kbuf  = (u16*)p; p += (size_t)MROWS * DIM * 2;
    u16* vbuf  = (u16*)p; p += (size_t)MROWS * DIM * 2;
    float* obuf = (float*)p; p += (size_t)MROWS * DIM * 4;
    u16* o2buf = (u16*)p;

    f32_to_bf16<<<MROWS * DIM / 1024, 256, 0, stream>>>(x, x_bf, MROWS * DIM);
    transpose_f32_bf16<<<dim3(1024, 4), 256, 0, stream>>>(Wq, wcatT + 0 * 1024 * 1024, 1024);
    transpose_f32_bf16<<<dim3(1024, 4), 256, 0, stream>>>(Wk, wcatT + 1 * 1024 * 1024, 1024);
    transpose_f32_bf16<<<dim3(1024, 4), 256, 0, stream>>>(Wv, wcatT + 2 * 1024 * 1024, 1024);
    transpose_f32_bf16<<<dim3(1024, 4), 256, 0, stream>>>(Wa, wcatT + 3 * 1024 * 1024, 1024);
    transpose_f32_bf16<<<dim3(1024, 4), 256, 0, stream>>>(Wg, wcatT + 4 * 1024 * 1024, 1024);
    transpose_f32_bf16<<<dim3(8, 4), 256, 0, stream>>>(Wb, wcatT + (size_t)5120 * 1024, 8);
    transpose_f32_bf16<<<dim3(1024, 4), 256, 0, stream>>>(Wo, woT, 1024);
    fill_zero_u16<<<(120 * 1024 + 255) / 256, 256, 0, stream>>>(wcatT + (size_t)5128 * 1024, 120 * 1024);

    gemm_bt<0><<<dim3(NCAT / 128, MROWS / 128), 256, 0, stream>>>(x_bf, wcatT, pre, MROWS, NCAT, DIM);

    conv_silu<<<MROWS, 256, 0, stream>>>(pre, qbuf, cqw, cqb, 1.0f, 0);
    conv_silu<<<MROWS, 256, 0, stream>>>(pre, kbuf, ckw, ckb, 0.08838834764831845f, 1024);
    conv_silu<<<MROWS, 256, 0, stream>>>(pre, vbuf, cvw, cvb, 1.0f, 2048);

    scan_chunked<<<64, 64, 0, stream>>>(qbuf, kbuf, vbuf, pre, ba, bb, obuf);

    ln_gate<<<MROWS, 256, 0, stream>>>(obuf, pre, lng, lnb, o2buf);

    gemm_bt<1><<<dim3(DIM / 128, MROWS / 128), 256, 0, stream>>>(o2buf, woT, d_out, MROWS, DIM, DIM);
}

// Round 11
// 1008.028 us; speedup vs baseline: 1.7021x; 1.7021x over previous
//
#include <hip/hip_runtime.h>

typedef unsigned short u16;
typedef __attribute__((ext_vector_type(8))) unsigned short ushort8;
typedef __attribute__((ext_vector_type(4))) unsigned short ushort4v;
typedef __attribute__((ext_vector_type(8))) short bf16x8;
typedef __attribute__((ext_vector_type(4))) float f32x4;
typedef __attribute__((ext_vector_type(2))) unsigned int uint2v;
typedef __attribute__((ext_vector_type(4))) unsigned int uint4v;

#define LB    2048
#define DIM   1024
#define NCAT  5248
#define MROWS 8192

__device__ __forceinline__ float b2f(u16 u) {
    unsigned int x = ((unsigned int)u) << 16;
    return __builtin_bit_cast(float, x);
}
__device__ __forceinline__ u16 f2b(float f) {
    unsigned int u = __builtin_bit_cast(unsigned int, f);
    u = u + 0x7FFFu + ((u >> 16) & 1u);
    return (u16)(u >> 16);
}
__device__ __forceinline__ float sigm(float x) { return 1.0f / (1.0f + __expf(-x)); }

// async global->LDS, 16B per lane; LDS dest = wave-uniform base + lane*16.
__device__ __forceinline__ void gload_lds16(const u16* g, u16* l) {
    __builtin_amdgcn_global_load_lds((const __attribute__((address_space(1))) void*)g,
                                     (__attribute__((address_space(3))) void*)l, 16, 0, 0);
}

#define MFMA(a, b, c) __builtin_amdgcn_mfma_f32_16x16x32_bf16((a), (b), (c), 0, 0, 0)

// ---------------- elementwise prep ----------------
__global__ void f32_to_bf16(const float* __restrict__ src, u16* __restrict__ dst, int n) {
    int i = (blockIdx.x * 256 + threadIdx.x) * 4;
    if (i >= n) return;
    float4 v = *(const float4*)(src + i);
    ushort4v u;
    u[0] = f2b(v.x); u[1] = f2b(v.y); u[2] = f2b(v.z); u[3] = f2b(v.w);
    *(ushort4v*)(dst + i) = u;
}

// src [1024, cols] f32  ->  dst[c*1024 + r] bf16   (grid: (cols, 4), block 256)
__global__ void transpose_f32_bf16(const float* __restrict__ src, u16* __restrict__ dst, int cols) {
    const int cidx = blockIdx.x;
    const int r = blockIdx.y * 256 + threadIdx.x;
    dst[(size_t)cidx * 1024 + r] = f2b(src[(size_t)r * cols + cidx]);
}

__global__ void fill_zero_u16(u16* __restrict__ dst, int n) {
    int i = blockIdx.x * 256 + threadIdx.x;
    if (i < n) dst[i] = 0;
}

// ---------------- bf16 MFMA GEMM (m97 structure):  C[M,N] = A[M,K] * Bt[N,K]^T ----------------
template <int OUT_IS_F32>
__global__ __launch_bounds__(256) void gemm_bt(const u16* __restrict__ A,
                                               const u16* __restrict__ Bt,
                                               void* __restrict__ Cv,
                                               int M, int N, int K) {
    __shared__ u16 lds_a[128 * 32];
    __shared__ u16 lds_b[128 * 32];
    const int tid = threadIdx.x;
    const int m0 = blockIdx.y * 128;
    const int n0 = blockIdx.x * 128;
    const int w = tid >> 6;
    const int l = tid & 63;
    const int wm = w >> 1, wn = w & 1;
    const int lr = l & 15, kg = l >> 4;

    f32x4 acc[4][4];
#pragma unroll
    for (int m = 0; m < 4; ++m)
#pragma unroll
        for (int n = 0; n < 4; ++n)
            acc[m][n] = f32x4{0.f, 0.f, 0.f, 0.f};

    const int scol = (l & 3) * 8;

    for (int kt = 0; kt < K; kt += 32) {
#pragma unroll
        for (int ld = 0; ld < 2; ++ld) {
            const int row = w * 32 + ld * 16 + (l >> 2);
            gload_lds16(A + (size_t)(m0 + row) * K + kt + scol, &lds_a[(w * 32 + ld * 16) * 32]);
            gload_lds16(Bt + (size_t)(n0 + row) * K + kt + scol, &lds_b[(w * 32 + ld * 16) * 32]);
        }
        __syncthreads();
        bf16x8 af[4], bfv[4];
#pragma unroll
        for (int m = 0; m < 4; ++m)
            af[m] = *(const bf16x8*)&lds_a[(wm * 64 + m * 16 + lr) * 32 + kg * 8];
#pragma unroll
        for (int n = 0; n < 4; ++n)
            bfv[n] = *(const bf16x8*)&lds_b[(wn * 64 + n * 16 + lr) * 32 + kg * 8];
#pragma unroll
        for (int m = 0; m < 4; ++m)
#pragma unroll
            for (int n = 0; n < 4; ++n)
                acc[m][n] = MFMA(af[m], bfv[n], acc[m][n]);
        __syncthreads();
    }

#pragma unroll
    for (int m = 0; m < 4; ++m) {
#pragma unroll
        for (int n = 0; n < 4; ++n) {
            const int col = n0 + wn * 64 + n * 16 + lr;
#pragma unroll
            for (int j = 0; j < 4; ++j) {
                const int row = m0 + wm * 64 + m * 16 + kg * 4 + j;
                if (OUT_IS_F32)
                    ((float*)Cv)[(size_t)row * N + col] = acc[m][n][j];
                else
                    ((u16*)Cv)[(size_t)row * N + col] = f2b(acc[m][n][j]);
            }
        }
    }
}

// ---------------- causal depthwise conv (K=4) + bias + SiLU (+scale) ----------------
__global__ __launch_bounds__(256) void conv_silu(const u16* __restrict__ pre,
                                                 u16* __restrict__ dst,
                                                 const float* __restrict__ w,
                                                 const float* __restrict__ bias,
                                                 float scale, int col_off) {
    const int row = blockIdx.x;       // b*L + l
    const int l = row & (LB - 1);
    const int ch = threadIdx.x * 4;
    const float4* wv = (const float4*)(w + ch * 4);
    float wt[4][4];
#pragma unroll
    for (int c = 0; c < 4; ++c) {
        float4 t = wv[c];
        wt[c][0] = t.x; wt[c][1] = t.y; wt[c][2] = t.z; wt[c][3] = t.w;
    }
    float acc[4] = {bias[ch + 0], bias[ch + 1], bias[ch + 2], bias[ch + 3]};
#pragma unroll
    for (int dd = 0; dd < 4; ++dd) {
        if (l - 3 + dd >= 0) {
            ushort4v vv = *(const ushort4v*)(pre + (size_t)(row - 3 + dd) * NCAT + col_off + ch);
#pragma unroll
            for (int c = 0; c < 4; ++c) acc[c] += b2f(vv[c]) * wt[c][dd];
        }
    }
    ushort4v outv;
#pragma unroll
    for (int c = 0; c < 4; ++c) {
        float a = acc[c];
        outv[c] = f2b(a * sigm(a) * scale);
    }
    *(ushort4v*)(dst + (size_t)row * DIM + ch) = outv;
}

// ---------------- chunked delta-rule scan (T=16), software-pipelined ----------------
// 64 blocks = (b, h, half-of-DV); 1 wave per block. Chunk c+1's global data is
// prefetched into registers during chunk c's compute. K/Q MFMA fragments are
// loaded DIRECTLY global->reg (no Kc/Qc LDS). Serial core prefetches ml rows
// into rotating register slots; beta sigmoid computed once by 16 lanes and
// broadcast via LDS; ubar packed in regs and written as 2 x b128.
__global__ __launch_bounds__(64, 1) void scan_chunked(const u16* __restrict__ qb,
                                                      const u16* __restrict__ kb,
                                                      const u16* __restrict__ vb,
                                                      const u16* __restrict__ pre,
                                                      const float* __restrict__ ba,
                                                      const float* __restrict__ bb,
                                                      float* __restrict__ o) {
    const int bid = blockIdx.x;        // 0..63
    const int bh = bid >> 1;           // 0..31
    const int half = bid & 1;
    const int h = bh & 7, b = bh >> 3;
    const int lane = threadIdx.x;      // 0..63
    const int lr = lane & 15, lg = lane >> 4;
    const size_t row0 = (size_t)b * LB;

    __shared__ u16 KT[128 * 36];      // [k][j] transposed K, j 16..35 zero
    __shared__ u16 S0b[64 * 136];     // [v][k] bf16 copy of S
    __shared__ u16 Ul[64 * 40];       // [v][j] ubar bf16, j 16..39 zero
    __shared__ u16 Ll[16 * 40];       // [t][j] masked QK gram bf16, j 16..39 zero
    __shared__ float c0T[64 * 20];    // [v][t]
    __shared__ float Gl[64 * 20];     // [v][t]
    __shared__ float ml[16 * 20];     // [t][t']
    __shared__ float Blf[16];         // beta sigmoid broadcast

    for (int i = lane; i < 64 * 136; i += 64) S0b[i] = 0;
    for (int i = lane; i < 64 * 40; i += 64) Ul[i] = 0;
    for (int i = lane; i < 16 * 40; i += 64) Ll[i] = 0;
    for (int i = lane; i < 128 * 36; i += 64) KT[i] = 0;

    const int ch = h * 128 + half * 64 + lane;
    const float bav = ba[ch];
    const float bbv = bb[h];

    const u16* kbase = kb + row0 * DIM + h * 128;
    const u16* qbase = qb + row0 * DIM + h * 128;
    const u16* vbase = vb + row0 * DIM + (size_t)ch;
    const u16* abase = pre + row0 * NCAT + 3072 + (size_t)ch;
    const u16* bbase = pre + row0 * NCAT + 5120 + h;
    float* obase = o + row0 * DIM + h * 128 + half * 64;

    f32x4 S[8][4];
#pragma unroll
    for (int kt = 0; kt < 8; ++kt)
#pragma unroll
        for (int vt = 0; vt < 4; ++vt)
            S[kt][vt] = f32x4{0.f, 0.f, 0.f, 0.f};

    // staged registers (chunk being prefetched)
    ushort8 kfN[4], qfN[4];           // MFMA frags for lane (lr, lg)
    unsigned int ktd[16];             // K columns 2*lane, 2*lane+1 (u16 pair per row)
    u16 vstg[16], astg[16], bstg1;

#define STAGE(cc) do {                                                              \
        _Pragma("unroll") for (int ks = 0; ks < 4; ++ks) {                          \
            kfN[ks] = *(const ushort8*)(kbase + (size_t)((cc) * 16 + lr) * DIM + lg * 8 + ks * 32); \
            qfN[ks] = *(const ushort8*)(qbase + (size_t)((cc) * 16 + lr) * DIM + lg * 8 + ks * 32); \
        }                                                                           \
        _Pragma("unroll") for (int t = 0; t < 16; ++t)                              \
            ktd[t] = *(const unsigned int*)(kbase + (size_t)((cc) * 16 + t) * DIM + lane * 2); \
        _Pragma("unroll") for (int t = 0; t < 16; ++t) {                            \
            vstg[t] = vbase[(size_t)((cc) * 16 + t) * DIM];                         \
            astg[t] = abase[(size_t)((cc) * 16 + t) * NCAT];                        \
        }                                                                           \
        if (lane < 16) bstg1 = bbase[(size_t)((cc) * 16 + lane) * NCAT];            \
    } while (0)

#define WRITE_KT() do {                                                             \
        _Pragma("unroll") for (int i = 0; i < 4; ++i) {                             \
            uint2v lo, hi;                                                          \
            lo[0] = __builtin_amdgcn_perm(ktd[4 * i + 1], ktd[4 * i + 0], 0x05040100u); \
            lo[1] = __builtin_amdgcn_perm(ktd[4 * i + 3], ktd[4 * i + 2], 0x05040100u); \
            hi[0] = __builtin_amdgcn_perm(ktd[4 * i + 1], ktd[4 * i + 0], 0x07060302u); \
            hi[1] = __builtin_amdgcn_perm(ktd[4 * i + 3], ktd[4 * i + 2], 0x07060302u); \
            *(uint2v*)&KT[(2 * lane) * 36 + i * 4] = lo;                            \
            *(uint2v*)&KT[(2 * lane + 1) * 36 + i * 4] = hi;                        \
        }                                                                           \
    } while (0)

#define LOADROW(dst, row) do {                                                      \
        float4 m0_ = *(const float4*)&ml[(row) * 20 + 0];                           \
        float4 m1_ = *(const float4*)&ml[(row) * 20 + 4];                           \
        float4 m2_ = *(const float4*)&ml[(row) * 20 + 8];                           \
        float4 m3_ = *(const float4*)&ml[(row) * 20 + 12];                          \
        dst[0] = m0_.x; dst[1] = m0_.y; dst[2] = m0_.z; dst[3] = m0_.w;             \
        dst[4] = m1_.x; dst[5] = m1_.y; dst[6] = m1_.z; dst[7] = m1_.w;             \
        dst[8] = m2_.x; dst[9] = m2_.y; dst[10] = m2_.z; dst[11] = m2_.w;           \
        dst[12] = m3_.x; dst[13] = m3_.y; dst[14] = m3_.z; dst[15] = m3_.w;         \
    } while (0)

#define SSTEP(t, CUR, NXT) do {                                                     \
        if ((t) < 15) LOADROW(NXT, (t) + 1);                                        \
        float e_ = ((t) == 0) ? c0v[0]                                              \
                              : G[((t) == 0) ? 0 : (t) - 1] * (c0v[t] + eacc[t]);   \
        float u_ = bf_[t] * (vf[t] - e_);                                           \
        float ub_ = u_ * __builtin_amdgcn_rcpf(G[t]);                               \
        unsigned int ub16_ = (unsigned int)f2b(ub_);                                \
        if ((t) & 1) upk[(t) >> 1] |= ub16_ << 16; else upk[(t) >> 1] = ub16_;      \
        _Pragma("unroll") for (int tp = (t) + 1; tp < 16; ++tp)                     \
            eacc[tp] = fmaf(ub_, CUR[tp], eacc[tp]);                                \
    } while (0)

    // prologue: stage chunk 0, build KT(0)
    STAGE(0);
    WRITE_KT();

#pragma unroll 1
    for (int c = 0; c < 128; ++c) {
        const int cn = (c + 1 < 128) ? c + 1 : 127;

        // ---- VAB process (chunk c) from staged regs ----
        float G[16], bf_[16], vf[16];
        if (lane < 16) Blf[lane] = sigm(b2f(bstg1) + bbv);
#pragma unroll
        for (int t = 0; t < 16; ++t) {
            vf[t] = b2f(vstg[t]);
            float aft = sigm(b2f(astg[t]) + bav);
            G[t] = (t == 0) ? aft : G[t - 1] * aft;
        }
#pragma unroll
        for (int q = 0; q < 4; ++q) {
            float4 gq = {G[4 * q], G[4 * q + 1], G[4 * q + 2], G[4 * q + 3]};
            *(float4*)&Gl[lane * 20 + 4 * q] = gq;
        }
#pragma unroll
        for (int t = 0; t < 16; ++t) bf_[t] = Blf[t];

        // ---- MFMA phase 1 (uses kfN/qfN = chunk c frags, S0b from prev chunk) ----
        f32x4 D2[4];
        {
            bf16x8 kfr[4], qfr[4];
#pragma unroll
            for (int ks = 0; ks < 4; ++ks) {
                kfr[ks] = __builtin_bit_cast(bf16x8, kfN[ks]);
                qfr[ks] = __builtin_bit_cast(bf16x8, qfN[ks]);
            }
#pragma unroll
            for (int vt = 0; vt < 4; ++vt) {
                bf16x8 sb[4];
#pragma unroll
                for (int ks = 0; ks < 4; ++ks)
                    sb[ks] = *(const bf16x8*)&S0b[(vt * 16 + lr) * 136 + lg * 8 + ks * 32];
                f32x4 d1 = f32x4{0.f, 0.f, 0.f, 0.f};
                f32x4 d2 = f32x4{0.f, 0.f, 0.f, 0.f};
#pragma unroll
                for (int ks = 0; ks < 4; ++ks) {
                    d1 = MFMA(kfr[ks], sb[ks], d1);   // D1[t][v] = k_t . S0[v,:]
                    d2 = MFMA(qfr[ks], sb[ks], d2);   // D2[t][v] = q_t . S0[v,:]
                }
#pragma unroll
                for (int j = 0; j < 4; ++j)
                    c0T[(vt * 16 + lr) * 20 + lg * 4 + j] = d1[j];
                D2[vt] = d2;
            }
            f32x4 d3 = f32x4{0.f, 0.f, 0.f, 0.f};
            f32x4 d4 = f32x4{0.f, 0.f, 0.f, 0.f};
#pragma unroll
            for (int ks = 0; ks < 4; ++ks) {
                d3 = MFMA(kfr[ks], kfr[ks], d3);   // m[t][t'] = k_t . k_t'
                d4 = MFMA(qfr[ks], kfr[ks], d4);   // N[t][j] = q_t . k_j
            }
#pragma unroll
            for (int j = 0; j < 4; ++j) {
                const int trow = lg * 4 + j;
                ml[trow * 20 + lr] = d3[j];
                Ll[trow * 40 + lr] = (lr <= trow) ? f2b(d4[j]) : (u16)0;
            }
        }

        // ---- issue chunk c+1 global loads (overwrites staged regs; all c-uses done) ----
        STAGE(cn);

        // ---- serial core (per-channel, lane = channel) ----
        {
            float c0v[16];
#pragma unroll
            for (int q = 0; q < 4; ++q) {
                float4 cq = *(const float4*)&c0T[lane * 20 + 4 * q];
                c0v[4 * q] = cq.x; c0v[4 * q + 1] = cq.y;
                c0v[4 * q + 2] = cq.z; c0v[4 * q + 3] = cq.w;
            }
            float eacc[16];
#pragma unroll
            for (int t = 0; t < 16; ++t) eacc[t] = 0.f;
            unsigned int upk[8];
            float mrA[16], mrB[16];
            LOADROW(mrA, 0);
            SSTEP(0, mrA, mrB);  SSTEP(1, mrB, mrA);
            SSTEP(2, mrA, mrB);  SSTEP(3, mrB, mrA);
            SSTEP(4, mrA, mrB);  SSTEP(5, mrB, mrA);
            SSTEP(6, mrA, mrB);  SSTEP(7, mrB, mrA);
            SSTEP(8, mrA, mrB);  SSTEP(9, mrB, mrA);
            SSTEP(10, mrA, mrB); SSTEP(11, mrB, mrA);
            SSTEP(12, mrA, mrB); SSTEP(13, mrB, mrA);
            SSTEP(14, mrA, mrB); SSTEP(15, mrB, mrA);
            uint4v u0, u1;
            u0[0] = upk[0]; u0[1] = upk[1]; u0[2] = upk[2]; u0[3] = upk[3];
            u1[0] = upk[4]; u1[1] = upk[5]; u1[2] = upk[6]; u1[3] = upk[7];
            *(ushort8*)&Ul[lane * 40] = __builtin_bit_cast(ushort8, u0);
            *(ushort8*)&Ul[lane * 40 + 8] = __builtin_bit_cast(ushort8, u1);
        }

        // ---- MFMA phase 2 ----
        bf16x8 ufr[4];
#pragma unroll
        for (int vt = 0; vt < 4; ++vt)
            ufr[vt] = *(const bf16x8*)&Ul[(vt * 16 + lr) * 40 + lg * 8];
#pragma unroll
        for (int kt = 0; kt < 8; ++kt) {
            uint2v alo = *(const uint2v*)&KT[(kt * 16 + lr) * 36 + lg * 8];
            uint2v ahi = *(const uint2v*)&KT[(kt * 16 + lr) * 36 + lg * 8 + 4];
            uint4v av;
            av[0] = alo[0]; av[1] = alo[1]; av[2] = ahi[0]; av[3] = ahi[1];
            bf16x8 afr = __builtin_bit_cast(bf16x8, av);
#pragma unroll
            for (int vt = 0; vt < 4; ++vt)
                S[kt][vt] = MFMA(afr, ufr[vt], S[kt][vt]);   // S[k][v] += k_j[k] ubar_j[v]
        }
        {
            bf16x8 lfr = *(const bf16x8*)&Ll[lr * 40 + lg * 8];
#pragma unroll
            for (int vt = 0; vt < 4; ++vt) {
                f32x4 d5 = MFMA(lfr, ufr[vt], D2[vt]);
                float4 gq = *(const float4*)&Gl[(vt * 16 + lr) * 20 + lg * 4];
                float gv[4] = {gq.x, gq.y, gq.z, gq.w};
#pragma unroll
                for (int j = 0; j < 4; ++j)
                    obase[(size_t)(c * 16 + lg * 4 + j) * DIM + vt * 16 + lr] = gv[j] * d5[j];
            }
        }
        // decay S by G_15 and refresh bf16 copy for next chunk
#pragma unroll
        for (int vt = 0; vt < 4; ++vt) {
            const float gT = Gl[(vt * 16 + lr) * 20 + 15];
#pragma unroll
            for (int kt = 0; kt < 8; ++kt) {
                S[kt][vt][0] *= gT; S[kt][vt][1] *= gT;
                S[kt][vt][2] *= gT; S[kt][vt][3] *= gT;
                ushort4v sv;
                sv[0] = f2b(S[kt][vt][0]); sv[1] = f2b(S[kt][vt][1]);
                sv[2] = f2b(S[kt][vt][2]); sv[3] = f2b(S[kt][vt][3]);
                *(ushort4v*)&S0b[(vt * 16 + lr) * 136 + kt * 16 + lg * 4] = sv;
            }
        }

        // ---- build KT for chunk c+1 from staged columns ----
        WRITE_KT();
    }
#undef STAGE
#undef WRITE_KT
#undef LOADROW
#undef SSTEP
}

// ---------------- LayerNorm(DV) + sigmoid gate -> bf16 ----------------
__global__ __launch_bounds__(256) void ln_gate(const float* __restrict__ o,
                                               const u16* __restrict__ pre,
                                               const float* __restrict__ ln_g,
                                               const float* __restrict__ ln_b,
                                               u16* __restrict__ o2) {
    const int row = blockIdx.x;
    const int tid = threadIdx.x;
    const int h = tid >> 5;
    const int lg = tid & 31;
    const int d0 = lg * 4;
    float4 x = *(const float4*)(o + (size_t)row * DIM + h * 128 + d0);
    float s = x.x + x.y + x.z + x.w;
    float ss = x.x * x.x + x.y * x.y + x.z * x.z + x.w * x.w;
#pragma unroll
    for (int m = 1; m <= 16; m <<= 1) {
        s += __shfl_xor(s, m);
        ss += __shfl_xor(ss, m);
    }
    const float mu = s * (1.f / 128.f);
    const float var = ss * (1.f / 128.f) - mu * mu;
    const float inv = rsqrtf(var + 1e-5f);
    ushort4v gp = *(const ushort4v*)(pre + (size_t)row * NCAT + 4096 + h * 128 + d0);
    float4 lg4 = *(const float4*)(ln_g + d0);
    float4 lb4 = *(const float4*)(ln_b + d0);
    float xv[4] = {x.x, x.y, x.z, x.w};
    float gv[4] = {lg4.x, lg4.y, lg4.z, lg4.w};
    float bv[4] = {lb4.x, lb4.y, lb4.z, lb4.w};
    ushort4v outv;
#pragma unroll
    for (int q = 0; q < 4; ++q) {
        float y = (xv[q] - mu) * inv * gv[q] + bv[q];
        y *= sigm(b2f(gp[q]));
        outv[q] = f2b(y);
    }
    *(ushort4v*)(o2 + (size_t)row * DIM + h * 128 + d0) = outv;
}

extern "C" void kernel_launch(void* const* d_in, const int* in_sizes, int n_in,
                              void* d_out, int out_size, void* d_ws, size_t ws_size,
                              hipStream_t stream) {
    const float* x   = (const float*)d_in[0];
    const float* Wq  = (const float*)d_in[1];
    const float* Wk  = (const float*)d_in[2];
    const float* Wv  = (const float*)d_in[3];
    const float* Wa  = (const float*)d_in[4];
    const float* ba  = (const float*)d_in[5];
    const float* Wb  = (const float*)d_in[6];
    const float* bb  = (const float*)d_in[7];
    const float* Wg  = (const float*)d_in[8];
    const float* Wo  = (const float*)d_in[9];
    const float* cqw = (const float*)d_in[10];
    const float* cqb = (const float*)d_in[11];
    const float* ckw = (const float*)d_in[12];
    const float* ckb = (const float*)d_in[13];
    const float* cvw = (const float*)d_in[14];
    const float* cvb = (const float*)d_in[15];
    const float* lng = (const float*)d_in[16];
    const float* lnb = (const float*)d_in[17];

    const size_t NEED = (size_t)MROWS * DIM * 2
                      + (size_t)NCAT * DIM * 2
                      + (size_t)DIM * DIM * 2
                      + (size_t)MROWS * NCAT * 2
                      + 3 * (size_t)MROWS * DIM * 2
                      + (size_t)MROWS * DIM * 4
                      + (size_t)MROWS * DIM * 2;
    if (ws_size < NEED) return;

    char* p = (char*)d_ws;
    u16* x_bf  = (u16*)p; p += (size_t)MROWS * DIM * 2;
    u16* wcatT = (u16*)p; p += (size_t)NCAT * DIM * 2;
    u16* woT   = (u16*)p; p += (size_t)DIM * DIM * 2;
    u16* pre   = (u16*)p; p += (size_t)MROWS * NCAT * 2;
    u16* qbuf  = (u16*)p; p += (size_t)MROWS * DIM * 2;
    u16* kbuf  = (u16*)p; p += (size_t)MROWS * DIM * 2;
    u16* vbuf  = (u16*)p; p += (size_t)MROWS * DIM * 2;
    float* obuf = (float*)p; p += (size_t)MROWS * DIM * 4;
    u16* o2buf = (u16*)p;

    f32_to_bf16<<<MROWS * DIM / 1024, 256, 0, stream>>>(x, x_bf, MROWS * DIM);
    transpose_f32_bf16<<<dim3(1024, 4), 256, 0, stream>>>(Wq, wcatT + 0 * 1024 * 1024, 1024);
    transpose_f32_bf16<<<dim3(1024, 4), 256, 0, stream>>>(Wk, wcatT + 1 * 1024 * 1024, 1024);
    transpose_f32_bf16<<<dim3(1024, 4), 256, 0, stream>>>(Wv, wcatT + 2 * 1024 * 1024, 1024);
    transpose_f32_bf16<<<dim3(1024, 4), 256, 0, stream>>>(Wa, wcatT + 3 * 1024 * 1024, 1024);
    transpose_f32_bf16<<<dim3(1024, 4), 256, 0, stream>>>(Wg, wcatT + 4 * 1024 * 1024, 1024);
    transpose_f32_bf16<<<dim3(8, 4), 256, 0, stream>>>(Wb, wcatT + (size_t)5120 * 1024, 8);
    transpose_f32_bf16<<<dim3(1024, 4), 256, 0, stream>>>(Wo, woT, 1024);
    fill_zero_u16<<<(120 * 1024 + 255) / 256, 256, 0, stream>>>(wcatT + (size_t)5128 * 1024, 120 * 1024);

    gemm_bt<0><<<dim3(NCAT / 128, MROWS / 128), 256, 0, stream>>>(x_bf, wcatT, pre, MROWS, NCAT, DIM);

    conv_silu<<<MROWS, 256, 0, stream>>>(pre, qbuf, cqw, cqb, 1.0f, 0);
    conv_silu<<<MROWS, 256, 0, stream>>>(pre, kbuf, ckw, ckb, 0.08838834764831845f, 1024);
    conv_silu<<<MROWS, 256, 0, stream>>>(pre, vbuf, cvw, cvb, 1.0f, 2048);

    scan_chunked<<<64, 64, 0, stream>>>(qbuf, kbuf, vbuf, pre, ba, bb, obuf);

    ln_gate<<<MROWS, 256, 0, stream>>>(obuf, pre, lng, lnb, o2buf);

    gemm_bt<1><<<dim3(DIM / 128, MROWS / 128), 256, 0, stream>>>(o2buf, woT, d_out, MROWS, DIM, DIM);
}